// Round 1
// baseline (1221.238 us; speedup 1.0000x reference)
//
#include <hip/hip_runtime.h>
#include <hip/hip_bf16.h>
#include <math.h>

#define VSZ 500000
#define BB  64
#define NN  512
#define EE  8192
#define HH  128
#define MM  (BB * NN)   // 32768 rows per branch

// ---------------------------------------------------------------------------
// GEMM: C[M x 128] = A[M x K] @ W[K x 128] (+bias)(+relu)
// If GATHER: A row r is concat(embP[erow[r]][0:128], featP[frow[r]][0:128]), K=256.
// BM=64, BN=128 (full width), BK=32. 256 threads, each computes 4 rows x 8 cols.
// ---------------------------------------------------------------------------
template<int K, bool GATHER, bool RELU>
__global__ __launch_bounds__(256) void gemm_kernel(
    const float* __restrict__ A,
    const int*   __restrict__ erow, const int* __restrict__ frow,
    const float* __restrict__ embP, const float* __restrict__ featP,
    const float* __restrict__ W,    const float* __restrict__ bias,
    float* __restrict__ C)
{
    __shared__ float As[64][33];    // +1 pad: conflict-free row reads
    __shared__ float Ws[32][132];   // +4 pad keeps float4 alignment, breaks stride-128
    const int tid = threadIdx.x;
    const int bm  = blockIdx.x * 64;
    const int ty  = tid >> 4;       // 0..15 row group (4 rows each)
    const int tx  = tid & 15;       // 0..15 col lane

    float acc[4][8];
#pragma unroll
    for (int i = 0; i < 4; i++)
#pragma unroll
        for (int j = 0; j < 8; j++) acc[i][j] = 0.f;

    const int ar = tid >> 2;          // 0..63  A-tile row
    const int ac = (tid & 3) * 8;     // 0,8,16,24 A-tile col base
    const int wr = tid >> 3;          // 0..31  W-tile row
    const int wc = (tid & 7) * 16;    // W-tile col base

    for (int k0 = 0; k0 < K; k0 += 32) {
        // ---- stage A tile (64x32) ----
        const float* asrc;
        if (GATHER) {
            const int grow = bm + ar;
            if (k0 < 128) asrc = embP  + (size_t)erow[grow] * HH + (k0 + ac);
            else          asrc = featP + (size_t)frow[grow] * HH + (k0 - 128 + ac);
        } else {
            asrc = A + (size_t)(bm + ar) * K + (k0 + ac);
        }
        float4 av0 = *(const float4*)(asrc);
        float4 av1 = *(const float4*)(asrc + 4);
        As[ar][ac + 0] = av0.x; As[ar][ac + 1] = av0.y;
        As[ar][ac + 2] = av0.z; As[ar][ac + 3] = av0.w;
        As[ar][ac + 4] = av1.x; As[ar][ac + 5] = av1.y;
        As[ar][ac + 6] = av1.z; As[ar][ac + 7] = av1.w;
        // ---- stage W tile (32x128) ----
        const float* wsrc = W + (size_t)(k0 + wr) * HH + wc;
        float4 w0 = ((const float4*)wsrc)[0];
        float4 w1 = ((const float4*)wsrc)[1];
        float4 w2 = ((const float4*)wsrc)[2];
        float4 w3 = ((const float4*)wsrc)[3];
        *(float4*)&Ws[wr][wc + 0]  = w0;
        *(float4*)&Ws[wr][wc + 4]  = w1;
        *(float4*)&Ws[wr][wc + 8]  = w2;
        *(float4*)&Ws[wr][wc + 12] = w3;
        __syncthreads();
#pragma unroll
        for (int kk = 0; kk < 32; kk++) {
            const float a0 = As[ty * 4 + 0][kk];
            const float a1 = As[ty * 4 + 1][kk];
            const float a2 = As[ty * 4 + 2][kk];
            const float a3 = As[ty * 4 + 3][kk];
#pragma unroll
            for (int j = 0; j < 8; j++) {
                const float w = Ws[kk][tx + j * 16];
                acc[0][j] += a0 * w;
                acc[1][j] += a1 * w;
                acc[2][j] += a2 * w;
                acc[3][j] += a3 * w;
            }
        }
        __syncthreads();
    }
#pragma unroll
    for (int i = 0; i < 4; i++) {
        float* crow = C + (size_t)(bm + ty * 4 + i) * HH;
#pragma unroll
        for (int j = 0; j < 8; j++) {
            const int col = tx + j * 16;
            float v = acc[i][j];
            if (bias) v += bias[col];
            if (RELU) v = fmaxf(v, 0.f);
            crow[col] = v;
        }
    }
}

// ---------------------------------------------------------------------------
// Build gather-row indices for the fused-gather GEMM.
// pos branch  (posidx==null): erow[i]=frow[i]=nodes[i]  (rows of embeddings/features)
// mal branch: erow[i] = b*N + posidx[i] (row of pos_emb), frow[i] = nodes[i]
// ---------------------------------------------------------------------------
__global__ void idx_kernel(const int* __restrict__ nodes,
                           const int* __restrict__ posidx,
                           int* __restrict__ erow, int* __restrict__ frow)
{
    const int i = blockIdx.x * 256 + threadIdx.x;   // 0..MM-1
    if (posidx) {
        erow[i] = (i & ~(NN - 1)) + posidx[i];      // b*N + posidx
        frow[i] = nodes[i];
    } else {
        const int v = nodes[i];
        erow[i] = v;
        frow[i] = v;
    }
}

// ---------------------------------------------------------------------------
// CSR build: indegree count -> per-graph exclusive scan -> scatter srcs by dst
// ---------------------------------------------------------------------------
__global__ void count_kernel(const int* __restrict__ edge, int* __restrict__ cnt)
{
    const int gid = blockIdx.x * 256 + threadIdx.x;   // 0..BB*EE-1
    const int b = gid >> 13;                          // EE = 8192 = 2^13
    const int e = gid & (EE - 1);
    const int dst = edge[(size_t)b * 2 * EE + EE + e];
    atomicAdd(&cnt[b * NN + dst], 1);
}

__global__ void scan_kernel(const int* __restrict__ cnt,
                            int* __restrict__ row, int* __restrict__ cur,
                            float* __restrict__ dinv)
{
    const int b = blockIdx.x;
    const int n = threadIdx.x;    // 512 threads
    __shared__ int s[NN];
    const int c = cnt[b * NN + n];
    s[n] = c;
    __syncthreads();
    for (int off = 1; off < NN; off <<= 1) {
        int v = (n >= off) ? s[n - off] : 0;
        __syncthreads();
        s[n] += v;
        __syncthreads();
    }
    const int excl = s[n] - c;
    row[b * (NN + 1) + n] = excl;
    cur[b * NN + n] = excl;
    if (n == NN - 1) row[b * (NN + 1) + NN] = s[NN - 1];
    dinv[b * NN + n] = rsqrtf((float)(c + 1));   // deg = indeg + self-loop
}

__global__ void scatter_kernel(const int* __restrict__ edge,
                               int* __restrict__ cur, int* __restrict__ esrc)
{
    const int gid = blockIdx.x * 256 + threadIdx.x;
    const int b = gid >> 13;
    const int e = gid & (EE - 1);
    const int src = edge[(size_t)b * 2 * EE + e];
    const int dst = edge[(size_t)b * 2 * EE + EE + e];
    const int p = atomicAdd(&cur[b * NN + dst], 1);
    esrc[b * EE + p] = src;
}

// ---------------------------------------------------------------------------
// GCN aggregate: out[n] = dinv[n]*(dinv[n]*h[n] + sum_{e:dst=n} dinv[src]*h[src]) + bias
// One wave per node, lane holds float2 of channels.
// ---------------------------------------------------------------------------
template<bool RELU>
__global__ __launch_bounds__(256) void agg_kernel(
    const float* __restrict__ h, const float* __restrict__ dinv,
    const int* __restrict__ row, const int* __restrict__ esrc,
    const float* __restrict__ bias, float* __restrict__ out)
{
    const int wave = threadIdx.x >> 6;
    const int lane = threadIdx.x & 63;
    const int node = blockIdx.x * 4 + wave;    // 0..MM-1
    const int b = node >> 9;                   // NN = 512 = 2^9
    const int n = node & (NN - 1);
    const float* hb = h + (size_t)b * NN * HH;
    const int c = lane * 2;

    const float dn = dinv[node];
    float2 self = *(const float2*)(hb + (size_t)n * HH + c);
    float a0 = self.x * dn, a1 = self.y * dn;

    const int r0 = row[b * (NN + 1) + n];
    const int r1 = row[b * (NN + 1) + n + 1];
    const int* es = esrc + (size_t)b * EE;
    const float* dv = dinv + b * NN;
    for (int e = r0; e < r1; e++) {
        const int s = es[e];
        const float ds = dv[s];
        float2 hv = *(const float2*)(hb + (size_t)s * HH + c);
        a0 += hv.x * ds;
        a1 += hv.y * ds;
    }
    float o0 = a0 * dn + bias[c];
    float o1 = a1 * dn + bias[c + 1];
    if (RELU) { o0 = fmaxf(o0, 0.f); o1 = fmaxf(o1, 0.f); }
    *(float2*)(out + (size_t)node * HH + c) = make_float2(o0, o1);
}

__global__ void root_kernel(const float* __restrict__ emb,
                            const int* __restrict__ root_idx,
                            float* __restrict__ roots)
{
    const int b = blockIdx.x;
    const int c = threadIdx.x;   // 128
    roots[b * HH + c] = emb[((size_t)b * NN + root_idx[b]) * HH + c];
}

// ---------------------------------------------------------------------------
// score(r) = sigmoid(relu(r@W1+b1)@W2+b2); 4 pairs: (pos,mlp),(pos,mlp1),(m1,mlp),(m2,mlp1)
// ---------------------------------------------------------------------------
__global__ __launch_bounds__(128) void score_kernel(
    const float* __restrict__ roots,
    const float* __restrict__ mW1, const float* __restrict__ mb1,
    const float* __restrict__ mW2, const float* __restrict__ mb2,
    const float* __restrict__ m1W1, const float* __restrict__ m1b1,
    const float* __restrict__ m1W2, const float* __restrict__ m1b2,
    float* __restrict__ out)
{
    const int blk  = blockIdx.x;          // 0..255
    const int pair = blk >> 6;            // 0..3
    const int b    = blk & 63;
    const int slot = (pair <= 1) ? 0 : (pair == 2 ? 1 : 2);
    const bool use1 = (pair == 1) || (pair == 3);
    const float* W1 = use1 ? m1W1 : mW1;
    const float* b1 = use1 ? m1b1 : mb1;
    const float* W2 = use1 ? m1W2 : mW2;
    const float* b2 = use1 ? m1b2 : mb2;
    const float* r  = roots + (size_t)slot * BB * HH + (size_t)b * HH;

    __shared__ float rs[HH];
    __shared__ float red[HH];
    const int j = threadIdx.x;
    rs[j] = r[j];
    __syncthreads();

    float acc = b1[j];
    for (int k = 0; k < HH; k++) acc += rs[k] * W1[k * HH + j];
    acc = fmaxf(acc, 0.f) * W2[j];

    red[j] = acc;
    __syncthreads();
    for (int off = 64; off >= 1; off >>= 1) {
        if (j < off) red[j] += red[j + off];
        __syncthreads();
    }
    if (j == 0) {
        const float z = red[0] + b2[0];
        out[pair * BB + b] = 1.f / (1.f + expf(-z));
    }
}

// ---------------------------------------------------------------------------
extern "C" void kernel_launch(void* const* d_in, const int* in_sizes, int n_in,
                              void* d_out, int out_size, void* d_ws, size_t ws_size,
                              hipStream_t stream)
{
    const int*   node_ids    = (const int*)  d_in[0];
    const int*   edge_pos    = (const int*)  d_in[1];
    const int*   root_idx    = (const int*)  d_in[2];
    const int*   mal_nodes1  = (const int*)  d_in[3];
    const int*   mal_posidx1 = (const int*)  d_in[4];
    const int*   edge_m1     = (const int*)  d_in[5];
    const int*   mal_nodes2  = (const int*)  d_in[6];
    const int*   mal_posidx2 = (const int*)  d_in[7];
    const int*   edge_m2     = (const int*)  d_in[8];
    const float* embeddings  = (const float*)d_in[9];
    const float* features    = (const float*)d_in[10];
    const float* fe_W1       = (const float*)d_in[11];
    const float* fe_b1       = (const float*)d_in[12];
    const float* fe_W2       = (const float*)d_in[13];
    const float* fe_b2       = (const float*)d_in[14];
    const float* g1_W        = (const float*)d_in[15];
    const float* g1_b        = (const float*)d_in[16];
    const float* g2_W        = (const float*)d_in[17];
    const float* g2_b        = (const float*)d_in[18];
    const float* mlp_W1      = (const float*)d_in[19];
    const float* mlp_b1      = (const float*)d_in[20];
    const float* mlp_W2      = (const float*)d_in[21];
    const float* mlp_b2      = (const float*)d_in[22];
    const float* mlp1_W1     = (const float*)d_in[23];
    const float* mlp1_b1     = (const float*)d_in[24];
    const float* mlp1_W2     = (const float*)d_in[25];
    const float* mlp1_b2     = (const float*)d_in[26];

    // ---- workspace layout ----
    char* w = (char*)d_ws;
    size_t off = 0;
    auto alloc = [&](size_t bytes) -> void* {
        void* p = w + off;
        off = (off + bytes + 255) & ~(size_t)255;
        return p;
    };
    const size_t BNH = (size_t)MM * HH;
    float* f_t0   = (float*)alloc(BNH * 4);            // fe hidden / gcn1 out
    float* f_x    = (float*)alloc(BNH * 4);            // fe out / mal emb out
    float* f_h    = (float*)alloc(BNH * 4);            // x@W
    float* f_pos  = (float*)alloc(BNH * 4);            // pos_emb (persists)
    float* f_dinv = (float*)alloc((size_t)MM * 4);
    int*   i_cnt  = (int*)  alloc((size_t)MM * 4);
    int*   i_row  = (int*)  alloc((size_t)BB * (NN + 1) * 4);
    int*   i_cur  = (int*)  alloc((size_t)MM * 4);
    int*   i_esrc = (int*)  alloc((size_t)BB * EE * 4);
    int*   i_erow = (int*)  alloc((size_t)MM * 4);
    int*   i_frow = (int*)  alloc((size_t)MM * 4);
    float* f_roots= (float*)alloc((size_t)3 * BB * HH * 4);

    auto run_branch = [&](const float* embBase, const int* nodes, const int* posidx,
                          const int* edges, float* out_emb) {
        // gather indices + CSR build
        hipMemsetAsync(i_cnt, 0, (size_t)MM * 4, stream);
        idx_kernel<<<MM / 256, 256, 0, stream>>>(nodes, posidx, i_erow, i_frow);
        count_kernel<<<(BB * EE) / 256, 256, 0, stream>>>(edges, i_cnt);
        scan_kernel<<<BB, NN, 0, stream>>>(i_cnt, i_row, i_cur, f_dinv);
        scatter_kernel<<<(BB * EE) / 256, 256, 0, stream>>>(edges, i_cur, i_esrc);
        // fe_mlp (gather fused into layer 1)
        gemm_kernel<256, true, true><<<MM / 64, 256, 0, stream>>>(
            nullptr, i_erow, i_frow, embBase, features, fe_W1, fe_b1, f_t0);
        gemm_kernel<128, false, false><<<MM / 64, 256, 0, stream>>>(
            f_t0, nullptr, nullptr, nullptr, nullptr, fe_W2, fe_b2, f_x);
        // GCN 1 (relu)
        gemm_kernel<128, false, false><<<MM / 64, 256, 0, stream>>>(
            f_x, nullptr, nullptr, nullptr, nullptr, g1_W, nullptr, f_h);
        agg_kernel<true><<<MM / 4, 256, 0, stream>>>(f_h, f_dinv, i_row, i_esrc, g1_b, f_t0);
        // GCN 2 (no relu)
        gemm_kernel<128, false, false><<<MM / 64, 256, 0, stream>>>(
            f_t0, nullptr, nullptr, nullptr, nullptr, g2_W, nullptr, f_h);
        agg_kernel<false><<<MM / 4, 256, 0, stream>>>(f_h, f_dinv, i_row, i_esrc, g2_b, out_emb);
    };

    // positive branch -> pos_emb (persists for mal branches)
    run_branch(embeddings, node_ids, nullptr, edge_pos, f_pos);
    root_kernel<<<BB, HH, 0, stream>>>(f_pos, root_idx, f_roots + 0);

    // malicious branch 1 (gathers x_embed from pos_emb)
    run_branch(f_pos, mal_nodes1, mal_posidx1, edge_m1, f_x);
    root_kernel<<<BB, HH, 0, stream>>>(f_x, root_idx, f_roots + (size_t)BB * HH);

    // malicious branch 2
    run_branch(f_pos, mal_nodes2, mal_posidx2, edge_m2, f_x);
    root_kernel<<<BB, HH, 0, stream>>>(f_x, root_idx, f_roots + (size_t)2 * BB * HH);

    // final score MLPs -> d_out (4 x 64 floats, return order)
    score_kernel<<<4 * BB, 128, 0, stream>>>(
        f_roots, mlp_W1, mlp_b1, mlp_W2, mlp_b2,
        mlp1_W1, mlp1_b1, mlp1_W2, mlp1_b2, (float*)d_out);
}